// Round 16
// baseline (1370.881 us; speedup 1.0000x reference)
//
#include <hip/hip_runtime.h>

#define B_TOT 1024
#define T_LEN 512
#define D_INP 128
#define H 100
#define HP 112      /* padded hidden (state vectors) */
#define HX 128      /* h1seq row stride in halves */
#define NP 448      /* padded gate dim = 4*HP */
#define FRAG_ELEMS 57344 /* 28*4*64*8 */

#define LOG2E  1.4426950408889634f
#define LOG2E2 2.8853900817779268f

typedef _Float16 half8 __attribute__((ext_vector_type(8)));
typedef float f32x4 __attribute__((ext_vector_type(4)));

#if __has_builtin(__builtin_amdgcn_exp2f)
__device__ __forceinline__ float EXP2(float x) { return __builtin_amdgcn_exp2f(x); }
#else
__device__ __forceinline__ float EXP2(float x) { return __expf(x * 0.6931471805599453f); }
#endif
#if __has_builtin(__builtin_amdgcn_rcpf)
__device__ __forceinline__ float RCP(float x) { return __builtin_amdgcn_rcpf(x); }
#else
__device__ __forceinline__ float RCP(float x) { return 1.0f / x; }
#endif

__device__ __forceinline__ float sig2(float zp)  { return RCP(1.0f + EXP2(-zp)); }
__device__ __forceinline__ float tanh2(float zp) { return 1.0f - 2.0f * RCP(EXP2(zp) + 1.0f); }
__device__ __forceinline__ float tanhc(float c)  { return 1.0f - 2.0f * RCP(EXP2(c * LOG2E2) + 1.0f); }
__device__ __forceinline__ float fast_sigmoid(float z) { return RCP(1.0f + EXP2(-z * LOG2E)); }
__device__ __forceinline__ float fast_tanh(float z)    { return 1.0f - 2.0f * RCP(EXP2(z * LOG2E2) + 1.0f); }

__device__ __forceinline__ unsigned pack2(float x, float y) {
    _Float16 a = (_Float16)x, b = (_Float16)y;
    unsigned short ua = __builtin_bit_cast(unsigned short, a);
    unsigned short ub = __builtin_bit_cast(unsigned short, b);
    return (unsigned)ua | ((unsigned)ub << 16);
}
__device__ __forceinline__ half8 pack8(float4 a, float4 b) {
    uint4 v = make_uint4(pack2(a.x, a.y), pack2(a.z, a.w), pack2(b.x, b.y), pack2(b.z, b.w));
    return __builtin_bit_cast(half8, v);
}
__device__ __forceinline__ unsigned swz(int row, int colbyte) {
    return ((unsigned)row * 256u + (unsigned)colbyte) ^ (unsigned)((row & 7) << 4);
}
// barrier that does NOT drain vmcnt (LDS ordering only; global prefetches keep flowing)
__device__ __forceinline__ void step_barrier() {
    asm volatile("s_waitcnt lgkmcnt(0)\n\ts_barrier" ::: "memory");
}

__global__ void init_states(float* s, int n) {
    int i = blockIdx.x * 256 + threadIdx.x;
    if (i < n) s[i] = 0.f;
}

// ---- prep: gate-permuted f16 B-fragments, PRESCALED by log2e (gate g: 2*log2e) ----
__global__ void prep_frags(const float* __restrict__ Wih1, const float* __restrict__ Wih2,
                           const float* __restrict__ Whh1, const float* __restrict__ Whh2,
                           const float* __restrict__ bih1, const float* __restrict__ bhh1,
                           const float* __restrict__ bih2, const float* __restrict__ bhh2,
                           _Float16* __restrict__ frags, float* __restrict__ biases)
{
    int i = blockIdx.x * 256 + threadIdx.x;
    if (i < 4 * FRAG_ELEMS) {
        int sec = i / FRAG_ELEMS, j = i % FRAG_ELEMS;
        int e = j & 7, lane = (j >> 3) & 63, kt = (j >> 9) & 3, nt = j >> 11;
        int l = lane & 15, jb = nt >> 2, g = nt & 3;
        int hcol = jb * 16 + l;
        int k = kt * 32 + (lane >> 4) * 8 + e;
        const float* W = (sec == 0) ? Wih1 : (sec == 1) ? Wih2 : (sec == 2) ? Whh1 : Whh2;
        int Kreal = (sec == 0) ? 128 : 100;
        float v = 0.f;
        if (hcol < 100 && k < Kreal)
            v = W[(g * 100 + hcol) * Kreal + k] * ((g == 2) ? LOG2E2 : LOG2E);
        frags[i] = (_Float16)v;
        return;
    }
    i -= 4 * FRAG_ELEMS;
    if (i < 2 * NP) {
        int layer = i / NP, cp = i % NP;
        int jb = cp >> 6, g = (cp >> 4) & 3, l = cp & 15;
        int hcol = jb * 16 + l;
        float v = 0.f;
        if (hcol < 100) {
            int G = g * 100 + hcol;
            v = (layer ? (bih2[G] + bhh2[G]) : (bih1[G] + bhh1[G]))
              * ((g == 2) ? LOG2E2 : LOG2E);
        }
        biases[i] = v;
    }
}

// ======== 2-stage superstep: blocks [0,64)=r1(fused gemm1, reads x), [64,128)=r2(fused gemm2) ========
// (512,2): 256 UNIFIED regs/wave on gfx950 — 4 waves/SIMD caps the unified file at 128 and spills.
template<int CT>
__global__ __launch_bounds__(512, 2) void superstep(
    const float* __restrict__ x,
    const _Float16* __restrict__ wihf1, const _Float16* __restrict__ whhf1,
    const float* __restrict__ bias1p,
    _Float16* __restrict__ h1w,
    _Float16* __restrict__ hst1, float* __restrict__ cst1,
    const _Float16* __restrict__ h1r,
    const _Float16* __restrict__ wihf2, const _Float16* __restrict__ whhf2,
    const float* __restrict__ bias2p,
    _Float16* __restrict__ hst2, float* __restrict__ cst2,
    float* __restrict__ out,
    int t0r1, int t0r2)
{
    __shared__ __align__(16) unsigned char smem[8192];
    const int tid = threadIdx.x;
    const int blk = blockIdx.x;

    unsigned char* hr0 = smem;
    unsigned char* hr1 = smem + 4096;
    const int w = tid >> 6, lane = tid & 63;
    const bool active = w < 7;
    const int jb = w, l = lane & 15, rg = lane >> 4;
    const int col = jb * 16 + l;

    unsigned rdo[4], wro[4];
    #pragma unroll
    for (int kt = 0; kt < 4; ++kt) rdo[kt] = swz(l, (kt * 32 + rg * 8) * 2);
    #pragma unroll
    for (int r = 0; r < 4; ++r) wro[r] = swz(rg * 4 + r, col * 2);

    if (blk < 64) {
        // ================= recur layer 1 (fused gemm1), chunk k =================
        if (t0r1 < 0) return;
        const int bg = blk, b0 = bg * 16;

        half8 bi[4][4], bf[4][4];
        float b1v[4];
        float cst[4];
        float4 xr[4][2];                 // raw f32 x_t fragment (packed to f16 at use)
        const float* xg_p = nullptr;     // bumped per step by D_INP
        _Float16* hs_p = nullptr;
        if (active) {
            #pragma unroll
            for (int g = 0; g < 4; ++g)
                #pragma unroll
                for (int kt = 0; kt < 4; ++kt) {
                    long o = (((long)(jb * 4 + g) * 4 + kt) * 64 + lane) * 8;
                    bi[g][kt] = *reinterpret_cast<const half8*>(wihf1 + o);
                    bf[g][kt] = *reinterpret_cast<const half8*>(whhf1 + o);
                }
            #pragma unroll
            for (int g = 0; g < 4; ++g) b1v[g] = bias1p[jb * 64 + g * 16 + l];
            xg_p = x + ((size_t)(b0 + l) * T_LEN + t0r1) * D_INP + rg * 8;
            hs_p = h1w + (size_t)bg * CT * 16 * HX + (size_t)(rg * 4) * HX + col;
            #pragma unroll
            for (int r = 0; r < 4; ++r)
                cst[r] = cst1[(size_t)(b0 + rg * 4 + r) * HP + col];
            #pragma unroll
            for (int kt = 0; kt < 4; ++kt) {
                xr[kt][0] = *reinterpret_cast<const float4*>(xg_p + kt * 32);
                xr[kt][1] = *reinterpret_cast<const float4*>(xg_p + kt * 32 + 4);
            }
            xg_p += D_INP;
        }
        if (tid < 64) {   // zero K-pad cols 112..127 of both ring slots
            int buf = tid >> 5, r2i = (tid & 31) >> 1, c8 = 112 + (tid & 1) * 8;
            *reinterpret_cast<uint4*>((buf ? hr1 : hr0) + swz(r2i, c8 * 2)) = make_uint4(0u, 0u, 0u, 0u);
        }
        if (tid >= 64 && tid < 288) {   // stage h[-1] -> slot1
            int i = tid - 64, row = i / 14, c8 = (i % 14) * 8;
            *reinterpret_cast<uint4*>(hr1 + swz(row, c8 * 2)) =
                *reinterpret_cast<const uint4*>(hst1 + (size_t)(b0 + row) * HP + c8);
        }
        __syncthreads();

        auto STEP1 = [&](int it, const unsigned char* rb, unsigned char* wb)
            __attribute__((always_inline)) {
            half8 af[4], ax[4];
            #pragma unroll
            for (int kt = 0; kt < 4; ++kt) {
                af[kt] = *reinterpret_cast<const half8*>(rb + rdo[kt]);
                ax[kt] = pack8(xr[kt][0], xr[kt][1]);   // f32->f16 at use (load had full step to land)
            }
            if (it + 1 < CT) {   // depth-1 prefetch of x[t+1] (raw)
                #pragma unroll
                for (int kt = 0; kt < 4; ++kt) {
                    xr[kt][0] = *reinterpret_cast<const float4*>(xg_p + kt * 32);
                    xr[kt][1] = *reinterpret_cast<const float4*>(xg_p + kt * 32 + 4);
                }
                xg_p += D_INP;
            }
            f32x4 acc[4];
            #pragma unroll
            for (int g = 0; g < 4; ++g)
                acc[g] = (f32x4){b1v[g], b1v[g], b1v[g], b1v[g]};
            #pragma unroll
            for (int kt = 0; kt < 4; ++kt)
                #pragma unroll
                for (int g = 0; g < 4; ++g)
                    acc[g] = __builtin_amdgcn_mfma_f32_16x16x32_f16(ax[kt], bi[g][kt], acc[g], 0, 0, 0);
            #pragma unroll
            for (int kt = 0; kt < 4; ++kt)
                #pragma unroll
                for (int g = 0; g < 4; ++g)
                    acc[g] = __builtin_amdgcn_mfma_f32_16x16x32_f16(af[kt], bf[g][kt], acc[g], 0, 0, 0);
            #pragma unroll
            for (int r = 0; r < 4; ++r) {
                float ig = sig2(acc[0][r]);
                float fg = sig2(acc[1][r]);
                float gg = tanh2(acc[2][r]);
                float og = sig2(acc[3][r]);
                float c = fg * cst[r] + ig * gg;
                cst[r] = c;
                float h = og * tanhc(c);
                _Float16 hf = (_Float16)h;
                *reinterpret_cast<_Float16*>(wb + wro[r]) = hf;
                *(hs_p + (size_t)r * HX) = hf;   // fire-and-forget
            }
            hs_p += (size_t)16 * HX;
        };

        for (int it = 0; it < CT; it += 2) {
            if (active) STEP1(it, hr1, hr0);
            step_barrier();
            if (active) STEP1(it + 1, hr0, hr1);
            step_barrier();
        }

        if (active) {
            #pragma unroll
            for (int r = 0; r < 4; ++r)
                cst1[(size_t)(b0 + rg * 4 + r) * HP + col] = cst[r];
        }
        if (tid < 224) {
            int row = tid / 14, c8 = (tid % 14) * 8;
            const unsigned char* sbuf = ((CT - 1) & 1) ? hr1 : hr0;
            *reinterpret_cast<uint4*>(hst1 + (size_t)(b0 + row) * HP + c8) =
                *reinterpret_cast<const uint4*>(sbuf + swz(row, c8 * 2));
        }
        return;
    }

    // ================= recur layer 2 (fused gemm2), chunk k-1 =================
    {
        if (t0r2 < 0) return;
        const int bg = blk - 64, b0 = bg * 16;

        half8 bi[4][4], bh[4][4];
        float b2v[4];
        float cst[4];
        half8 hP[4];
        const _Float16* hb_p = nullptr;
        float* out_p = nullptr;
        if (active) {
            #pragma unroll
            for (int g = 0; g < 4; ++g)
                #pragma unroll
                for (int kt = 0; kt < 4; ++kt) {
                    long o = (((long)(jb * 4 + g) * 4 + kt) * 64 + lane) * 8;
                    bi[g][kt] = *reinterpret_cast<const half8*>(wihf2 + o);
                    bh[g][kt] = *reinterpret_cast<const half8*>(whhf2 + o);
                }
            #pragma unroll
            for (int g = 0; g < 4; ++g) b2v[g] = bias2p[jb * 64 + g * 16 + l];
            hb_p = h1r + (size_t)bg * CT * 16 * HX + (size_t)l * HX + rg * 8;
            out_p = out + ((size_t)(b0 + rg * 4) * T_LEN + t0r2) * H + col;
            #pragma unroll
            for (int r = 0; r < 4; ++r)
                cst[r] = cst2[(size_t)(b0 + rg * 4 + r) * HP + col];
            #pragma unroll
            for (int kt = 0; kt < 4; ++kt)
                hP[kt] = *reinterpret_cast<const half8*>(hb_p + kt * 32);
        }
        if (tid < 64) {
            int buf = tid >> 5, r2i = (tid & 31) >> 1, c8 = 112 + (tid & 1) * 8;
            *reinterpret_cast<uint4*>((buf ? hr1 : hr0) + swz(r2i, c8 * 2)) = make_uint4(0u, 0u, 0u, 0u);
        }
        if (tid >= 64 && tid < 288) {
            int i = tid - 64, row = i / 14, c8 = (i % 14) * 8;
            *reinterpret_cast<uint4*>(hr1 + swz(row, c8 * 2)) =
                *reinterpret_cast<const uint4*>(hst2 + (size_t)(b0 + row) * HP + c8);
        }
        __syncthreads();

        auto STEP2 = [&](int it, const unsigned char* rb, unsigned char* wb)
            __attribute__((always_inline)) {
            half8 af2[4];
            #pragma unroll
            for (int kt = 0; kt < 4; ++kt)
                af2[kt] = *reinterpret_cast<const half8*>(rb + rdo[kt]);
            f32x4 acc[4];
            #pragma unroll
            for (int g = 0; g < 4; ++g)
                acc[g] = (f32x4){b2v[g], b2v[g], b2v[g], b2v[g]};
            // ring-independent half: h1[t] x Wih2 (registers only)
            #pragma unroll
            for (int kt = 0; kt < 4; ++kt)
                #pragma unroll
                for (int g = 0; g < 4; ++g)
                    acc[g] = __builtin_amdgcn_mfma_f32_16x16x32_f16(hP[kt], bi[g][kt], acc[g], 0, 0, 0);
            if (it + 1 < CT) {   // depth-1 prefetch of h1[t+1]
                hb_p += (size_t)16 * HX;
                #pragma unroll
                for (int kt = 0; kt < 4; ++kt)
                    hP[kt] = *reinterpret_cast<const half8*>(hb_p + kt * 32);
            }
            #pragma unroll
            for (int kt = 0; kt < 4; ++kt)
                #pragma unroll
                for (int g = 0; g < 4; ++g)
                    acc[g] = __builtin_amdgcn_mfma_f32_16x16x32_f16(af2[kt], bh[g][kt], acc[g], 0, 0, 0);
            #pragma unroll
            for (int r = 0; r < 4; ++r) {
                float ig = sig2(acc[0][r]);
                float fg = sig2(acc[1][r]);
                float gg = tanh2(acc[2][r]);
                float og = sig2(acc[3][r]);
                float c = fg * cst[r] + ig * gg;
                cst[r] = c;
                float h = og * tanhc(c);
                *reinterpret_cast<_Float16*>(wb + wro[r]) = (_Float16)h;
                if (col < H) *(out_p + (size_t)r * T_LEN * H) = h;   // fire-and-forget
            }
            out_p += H;
        };

        for (int it = 0; it < CT; it += 2) {
            if (active) STEP2(it, hr1, hr0);
            step_barrier();
            if (active) STEP2(it + 1, hr0, hr1);
            step_barrier();
        }

        if (active) {
            #pragma unroll
            for (int r = 0; r < 4; ++r)
                cst2[(size_t)(b0 + rg * 4 + r) * HP + col] = cst[r];
        }
        if (tid < 224) {
            int row = tid / 14, c8 = (tid % 14) * 8;
            const unsigned char* sbuf = ((CT - 1) & 1) ? hr1 : hr0;
            *reinterpret_cast<uint4*>(hst2 + (size_t)(b0 + row) * HP + c8) =
                *reinterpret_cast<const uint4*>(sbuf + swz(row, c8 * 2));
        }
    }
}

// ---------------- fp32 fallback (tiny workspace only) ----------------
__global__ __launch_bounds__(256) void lstm2_persistent(
    const float* __restrict__ x,
    const float* __restrict__ W_ih1, const float* __restrict__ W_hh1,
    const float* __restrict__ b_ih1, const float* __restrict__ b_hh1,
    const float* __restrict__ W_ih2, const float* __restrict__ W_hh2,
    const float* __restrict__ b_ih2, const float* __restrict__ b_hh2,
    float* __restrict__ out)
{
    __shared__ float s_x[4][D_INP];
    __shared__ float s_h1[4][H], s_c1[4][H], s_h2[4][H], s_c2[4][H];
    __shared__ float s_g[4][400];
    __shared__ float s_b1[400], s_b2[400];
    const int tid = threadIdx.x;
    const int row0 = blockIdx.x * 4;
    for (int i = tid; i < 400; i += 256) { s_b1[i] = b_ih1[i] + b_hh1[i]; s_b2[i] = b_ih2[i] + b_hh2[i]; }
    for (int i = tid; i < 4 * H; i += 256) { int r = i / H, jj = i % H;
        s_h1[r][jj] = 0.f; s_c1[r][jj] = 0.f; s_h2[r][jj] = 0.f; s_c2[r][jj] = 0.f; }
    __syncthreads();
    for (int t = 0; t < T_LEN; ++t) {
        for (int i = tid; i < 4 * D_INP; i += 256) { int r = i >> 7, d = i & 127;
            s_x[r][d] = x[((size_t)(row0 + r) * T_LEN + t) * D_INP + d]; }
        __syncthreads();
        for (int g = tid; g < 400; g += 256) {
            float a0, a1, a2, a3; a0 = a1 = a2 = a3 = s_b1[g];
            const float4* wi = reinterpret_cast<const float4*>(W_ih1 + (size_t)g * D_INP);
            for (int d4 = 0; d4 < D_INP / 4; ++d4) {
                float4 wv = wi[d4];
                float4 v0 = *reinterpret_cast<const float4*>(&s_x[0][d4 * 4]);
                float4 v1 = *reinterpret_cast<const float4*>(&s_x[1][d4 * 4]);
                float4 v2 = *reinterpret_cast<const float4*>(&s_x[2][d4 * 4]);
                float4 v3 = *reinterpret_cast<const float4*>(&s_x[3][d4 * 4]);
                a0 += wv.x*v0.x + wv.y*v0.y + wv.z*v0.z + wv.w*v0.w;
                a1 += wv.x*v1.x + wv.y*v1.y + wv.z*v1.z + wv.w*v1.w;
                a2 += wv.x*v2.x + wv.y*v2.y + wv.z*v2.z + wv.w*v2.w;
                a3 += wv.x*v3.x + wv.y*v3.y + wv.z*v3.z + wv.w*v3.w;
            }
            const float4* wh = reinterpret_cast<const float4*>(W_hh1 + (size_t)g * H);
            for (int k4 = 0; k4 < H / 4; ++k4) {
                float4 wv = wh[k4];
                float4 v0 = *reinterpret_cast<const float4*>(&s_h1[0][k4 * 4]);
                float4 v1 = *reinterpret_cast<const float4*>(&s_h1[1][k4 * 4]);
                float4 v2 = *reinterpret_cast<const float4*>(&s_h1[2][k4 * 4]);
                float4 v3 = *reinterpret_cast<const float4*>(&s_h1[3][k4 * 4]);
                a0 += wv.x*v0.x + wv.y*v0.y + wv.z*v0.z + wv.w*v0.w;
                a1 += wv.x*v1.x + wv.y*v1.y + wv.z*v1.z + wv.w*v1.w;
                a2 += wv.x*v2.x + wv.y*v2.y + wv.z*v2.z + wv.w*v2.w;
                a3 += wv.x*v3.x + wv.y*v3.y + wv.z*v3.z + wv.w*v3.w;
            }
            s_g[0][g] = a0; s_g[1][g] = a1; s_g[2][g] = a2; s_g[3][g] = a3;
        }
        __syncthreads();
        for (int idx = tid; idx < 4 * H; idx += 256) {
            int r = idx / H, jj = idx % H;
            float ig = fast_sigmoid(s_g[r][jj]);
            float fg = fast_sigmoid(s_g[r][H + jj]);
            float gg = fast_tanh(s_g[r][2 * H + jj]);
            float og = fast_sigmoid(s_g[r][3 * H + jj]);
            float cc = fg * s_c1[r][jj] + ig * gg;
            s_c1[r][jj] = cc; s_h1[r][jj] = og * fast_tanh(cc);
        }
        __syncthreads();
        for (int g = tid; g < 400; g += 256) {
            float a0, a1, a2, a3; a0 = a1 = a2 = a3 = s_b2[g];
            const float4* wi = reinterpret_cast<const float4*>(W_ih2 + (size_t)g * H);
            const float4* wh = reinterpret_cast<const float4*>(W_hh2 + (size_t)g * H);
            for (int k4 = 0; k4 < H / 4; ++k4) {
                float4 wv = wi[k4];
                float4 v0 = *reinterpret_cast<const float4*>(&s_h1[0][k4 * 4]);
                float4 v1 = *reinterpret_cast<const float4*>(&s_h1[1][k4 * 4]);
                float4 v2 = *reinterpret_cast<const float4*>(&s_h1[2][k4 * 4]);
                float4 v3 = *reinterpret_cast<const float4*>(&s_h1[3][k4 * 4]);
                a0 += wv.x*v0.x + wv.y*v0.y + wv.z*v0.z + wv.w*v0.w;
                a1 += wv.x*v1.x + wv.y*v1.y + wv.z*v1.z + wv.w*v1.w;
                a2 += wv.x*v2.x + wv.y*v2.y + wv.z*v2.z + wv.w*v2.w;
                a3 += wv.x*v3.x + wv.y*v3.y + wv.z*v3.z + wv.w*v3.w;
            }
            for (int k4 = 0; k4 < H / 4; ++k4) {
                float4 wv = wh[k4];
                float4 v0 = *reinterpret_cast<const float4*>(&s_h2[0][k4 * 4]);
                float4 v1 = *reinterpret_cast<const float4*>(&s_h2[1][k4 * 4]);
                float4 v2 = *reinterpret_cast<const float4*>(&s_h2[2][k4 * 4]);
                float4 v3 = *reinterpret_cast<const float4*>(&s_h2[3][k4 * 4]);
                a0 += wv.x*v0.x + wv.y*v0.y + wv.z*v0.z + wv.w*v0.w;
                a1 += wv.x*v1.x + wv.y*v1.y + wv.z*v1.z + wv.w*v1.w;
                a2 += wv.x*v2.x + wv.y*v2.y + wv.z*v2.z + wv.w*v2.w;
                a3 += wv.x*v3.x + wv.y*v3.y + wv.z*v3.z + wv.w*v3.w;
            }
            s_g[0][g] = a0; s_g[1][g] = a1; s_g[2][g] = a2; s_g[3][g] = a3;
        }
        __syncthreads();
        for (int idx = tid; idx < 4 * H; idx += 256) {
            int r = idx / H, jj = idx % H;
            float ig = fast_sigmoid(s_g[r][jj]);
            float fg = fast_sigmoid(s_g[r][H + jj]);
            float gg = fast_tanh(s_g[r][2 * H + jj]);
            float og = fast_sigmoid(s_g[r][3 * H + jj]);
            float cc = fg * s_c2[r][jj] + ig * gg;
            s_c2[r][jj] = cc;
            float hn = og * fast_tanh(cc);
            s_h2[r][jj] = hn;
            out[((size_t)(row0 + r) * T_LEN + t) * H + jj] = hn;
        }
        __syncthreads();
    }
}

// ---------------- host ----------------
template<int CT>
static void run_pipeline(const float* x, float* out,
                         _Float16* h1a, _Float16* h1b,
                         float* cst1, float* cst2, _Float16* hst1, _Float16* hst2,
                         const _Float16* wihf1, const _Float16* wihf2,
                         const _Float16* whhf1, const _Float16* whhf2,
                         const float* bias1, const float* bias2,
                         hipStream_t stream)
{
    const int nCh = T_LEN / CT;
    for (int k = 0; k <= nCh; ++k) {
        int t0r1 = (k < nCh) ? k * CT : -1;
        int t0r2 = (k >= 1) ? (k - 1) * CT : -1;
        _Float16* h1w = (k & 1) ? h1b : h1a;                 // chunk k parity
        const _Float16* h1r = (k & 1) ? h1a : h1b;           // chunk k-1 parity
        superstep<CT><<<128, 512, 0, stream>>>(
            x, wihf1, whhf1, bias1, h1w, hst1, cst1,
            h1r, wihf2, whhf2, bias2, hst2, cst2, out,
            t0r1, t0r2);
    }
}

extern "C" void kernel_launch(void* const* d_in, const int* in_sizes, int n_in,
                              void* d_out, int out_size, void* d_ws, size_t ws_size,
                              hipStream_t stream) {
    const float* x     = (const float*)d_in[0];
    const float* W_ih1 = (const float*)d_in[1];
    const float* W_hh1 = (const float*)d_in[2];
    const float* b_ih1 = (const float*)d_in[3];
    const float* b_hh1 = (const float*)d_in[4];
    const float* W_ih2 = (const float*)d_in[5];
    const float* W_hh2 = (const float*)d_in[6];
    const float* b_ih2 = (const float*)d_in[7];
    const float* b_hh2 = (const float*)d_in[8];
    float* out = (float*)d_out;

    auto need = [](int CT) -> size_t {
        return 2ull * B_TOT * CT * HX * 2         // h1seq double-buffered f16
             + 2ull * B_TOT * HP * 4              // c states f32
             + 2ull * B_TOT * HP * 2              // h states f16
             + 4ull * FRAG_ELEMS * 2              // weight frags f16
             + 2ull * NP * 4                      // biases
             + 256;                               // slack
    };

    int CT = 0;
    if (ws_size >= need(64)) CT = 64;
    else if (ws_size >= need(32)) CT = 32;

    if (CT == 0) {
        lstm2_persistent<<<B_TOT / 4, 256, 0, stream>>>(
            x, W_ih1, W_hh1, b_ih1, b_hh1, W_ih2, W_hh2, b_ih2, b_hh2, out);
        return;
    }

    char* p = (char*)d_ws;
    size_t xchunk = (size_t)B_TOT * (size_t)CT;
    _Float16* h1a = (_Float16*)p;     p += xchunk * HX * 2;
    _Float16* h1b = (_Float16*)p;     p += xchunk * HX * 2;
    float* cst1 = (float*)p;          p += (size_t)B_TOT * HP * 4;
    float* cst2 = (float*)p;          p += (size_t)B_TOT * HP * 4;
    _Float16* hst1 = (_Float16*)p;    p += (size_t)B_TOT * HP * 2;
    _Float16* hst2 = (_Float16*)p;    p += (size_t)B_TOT * HP * 2;
    _Float16* frags = (_Float16*)p;   p += 4ull * FRAG_ELEMS * 2;
    float* biases = (float*)p;        p += 2ull * NP * 4;

    const _Float16* wihf1 = frags;
    const _Float16* wihf2 = frags + FRAG_ELEMS;
    const _Float16* whhf1 = frags + 2ull * FRAG_ELEMS;
    const _Float16* whhf2 = frags + 3ull * FRAG_ELEMS;
    const float* bias1 = biases;
    const float* bias2 = biases + NP;

    // zero c1,c2 (f32) + h1,h2 (f16) — contiguous: 3*B*HP f32-words
    int nzero = 3 * B_TOT * HP;
    init_states<<<(nzero + 255) / 256, 256, 0, stream>>>(cst1, nzero);

    int nprep = 4 * FRAG_ELEMS + 2 * NP;
    prep_frags<<<(nprep + 255) / 256, 256, 0, stream>>>(
        W_ih1, W_ih2, W_hh1, W_hh2, b_ih1, b_hh1, b_ih2, b_hh2, frags, biases);

    if (CT == 64)
        run_pipeline<64>(x, out, h1a, h1b, cst1, cst2, hst1, hst2,
                         wihf1, wihf2, whhf1, whhf2, bias1, bias2, stream);
    else
        run_pipeline<32>(x, out, h1a, h1b, cst1, cst2, hst1, hst2,
                         wihf1, wihf2, whhf1, whhf2, bias1, bias2, stream);
}

// Round 17
// 784.944 us; speedup vs baseline: 1.7465x; 1.7465x over previous
//
#include <hip/hip_runtime.h>

#define B_TOT 1024
#define T_LEN 512
#define D_INP 128
#define H 100
#define HP 112      /* padded hidden (state vectors) */
#define HX 128      /* h1seq row stride in halves */
#define NP 448      /* padded gate dim = 4*HP */
#define NT_TILES 28 /* NP/16 */
#define FRAG_ELEMS 57344 /* 28*4*64*8 */

#define LOG2E  1.4426950408889634f
#define LOG2E2 2.8853900817779268f

typedef _Float16 half8 __attribute__((ext_vector_type(8)));
typedef _Float16 half4 __attribute__((ext_vector_type(4)));
typedef float f32x4 __attribute__((ext_vector_type(4)));

#if __has_builtin(__builtin_amdgcn_exp2f)
__device__ __forceinline__ float EXP2(float x) { return __builtin_amdgcn_exp2f(x); }
#else
__device__ __forceinline__ float EXP2(float x) { return __expf(x * 0.6931471805599453f); }
#endif
#if __has_builtin(__builtin_amdgcn_rcpf)
__device__ __forceinline__ float RCP(float x) { return __builtin_amdgcn_rcpf(x); }
#else
__device__ __forceinline__ float RCP(float x) { return 1.0f / x; }
#endif

__device__ __forceinline__ float sig2(float zp)  { return RCP(1.0f + EXP2(-zp)); }
__device__ __forceinline__ float tanh2(float zp) { return 1.0f - 2.0f * RCP(EXP2(zp) + 1.0f); }
__device__ __forceinline__ float tanhc(float c)  { return 1.0f - 2.0f * RCP(EXP2(c * LOG2E2) + 1.0f); }
__device__ __forceinline__ float fast_sigmoid(float z) { return RCP(1.0f + EXP2(-z * LOG2E)); }
__device__ __forceinline__ float fast_tanh(float z)    { return 1.0f - 2.0f * RCP(EXP2(z * LOG2E2) + 1.0f); }

__device__ __forceinline__ unsigned pack2(float x, float y) {
    _Float16 a = (_Float16)x, b = (_Float16)y;
    unsigned short ua = __builtin_bit_cast(unsigned short, a);
    unsigned short ub = __builtin_bit_cast(unsigned short, b);
    return (unsigned)ua | ((unsigned)ub << 16);
}
__device__ __forceinline__ unsigned swz(int row, int colbyte) {
    return ((unsigned)row * 256u + (unsigned)colbyte) ^ (unsigned)((row & 7) << 4);
}
// barrier that does NOT drain vmcnt (LDS ordering only; global prefetches keep flowing)
__device__ __forceinline__ void step_barrier() {
    asm volatile("s_waitcnt lgkmcnt(0)\n\ts_barrier" ::: "memory");
}

__global__ void init_states(float* s, int n) {
    int i = blockIdx.x * 256 + threadIdx.x;
    if (i < n) s[i] = 0.f;
}

// ---- prep: gate-permuted f16 B-fragments, PRESCALED by log2e (gate g: 2*log2e) ----
__global__ void prep_frags(const float* __restrict__ Wih1, const float* __restrict__ Wih2,
                           const float* __restrict__ Whh1, const float* __restrict__ Whh2,
                           const float* __restrict__ bih1, const float* __restrict__ bhh1,
                           const float* __restrict__ bih2, const float* __restrict__ bhh2,
                           _Float16* __restrict__ frags, float* __restrict__ biases)
{
    int i = blockIdx.x * 256 + threadIdx.x;
    if (i < 4 * FRAG_ELEMS) {
        int sec = i / FRAG_ELEMS, j = i % FRAG_ELEMS;
        int e = j & 7, lane = (j >> 3) & 63, kt = (j >> 9) & 3, nt = j >> 11;
        int l = lane & 15, jb = nt >> 2, g = nt & 3;
        int hcol = jb * 16 + l;
        int k = kt * 32 + (lane >> 4) * 8 + e;
        const float* W = (sec == 0) ? Wih1 : (sec == 1) ? Wih2 : (sec == 2) ? Whh1 : Whh2;
        int Kreal = (sec == 0) ? 128 : 100;
        float v = 0.f;
        if (hcol < 100 && k < Kreal)
            v = W[(g * 100 + hcol) * Kreal + k] * ((g == 2) ? LOG2E2 : LOG2E);
        frags[i] = (_Float16)v;
        return;
    }
    i -= 4 * FRAG_ELEMS;
    if (i < 2 * NP) {
        int layer = i / NP, cp = i % NP;
        int jb = cp >> 6, g = (cp >> 4) & 3, l = cp & 15;
        int hcol = jb * 16 + l;
        float v = 0.f;
        if (hcol < 100) {
            int G = g * 100 + hcol;
            v = (layer ? (bih2[G] + bhh2[G]) : (bih1[G] + bhh1[G]))
              * ((g == 2) ? LOG2E2 : LOG2E);
        }
        biases[i] = v;
    }
}

// ================== pipelined superstep: blocks [0,64)=r1, [64,128)=r2(fused), [128,..)=gemm ==================
// (512,2): 256 UNIFIED regs/wave on gfx950 — 4 waves/SIMD caps the unified file at 128 and spills.
template<int CT>
__global__ __launch_bounds__(512, 2) void superstep(
    const float* __restrict__ x,
    const _Float16* __restrict__ wfrag1, const float* __restrict__ bias1,
    _Float16* __restrict__ X1w, const _Float16* __restrict__ X1r,
    const _Float16* __restrict__ whhf1, _Float16* __restrict__ h1w,
    _Float16* __restrict__ hst1, float* __restrict__ cst1,
    const _Float16* __restrict__ h1r,
    const _Float16* __restrict__ wihf2, const _Float16* __restrict__ whhf2,
    const float* __restrict__ bias2p,
    _Float16* __restrict__ hst2, float* __restrict__ cst2,
    float* __restrict__ out,
    int t0g, int r1on, int t0r2)
{
    constexpr int LOG2CT = (CT == 128) ? 7 : (CT == 64) ? 6 : 5;
    __shared__ __align__(16) unsigned char smem[65536 + 2048];
    const int tid = threadIdx.x;
    const int blk = blockIdx.x;

    if (blk < 64) {
        // ================= recur layer 1, chunk k-1 =================
        if (!r1on) return;
        unsigned char* hr0 = smem;
        unsigned char* hr1 = smem + 4096;
        const int w = tid >> 6, lane = tid & 63;
        const bool active = w < 7;
        const int jb = w, l = lane & 15, rg = lane >> 4;
        const int bg = blk, b0 = bg * 16;
        const int col = jb * 16 + l;

        unsigned rdo[4], wro[4];
        #pragma unroll
        for (int kt = 0; kt < 4; ++kt) rdo[kt] = swz(l, (kt * 32 + rg * 8) * 2);
        #pragma unroll
        for (int r = 0; r < 4; ++r) wro[r] = swz(rg * 4 + r, col * 2);

        half8 bf[4][4];
        float cst[4];
        half4 xP[4];
        const _Float16* x_p = nullptr;
        _Float16* hs_p = nullptr;
        if (active) {
            #pragma unroll
            for (int g = 0; g < 4; ++g)
                #pragma unroll
                for (int kt = 0; kt < 4; ++kt)
                    bf[g][kt] = *reinterpret_cast<const half8*>(
                        whhf1 + (((long)(jb * 4 + g) * 4 + kt) * 64 + lane) * 8);
            x_p = X1r + (size_t)bg * CT * 16 * NP + (size_t)(rg * 4) * NP + jb * 64 + l * 4;
            hs_p = h1w + (size_t)bg * CT * 16 * HX + (size_t)(rg * 4) * HX + col;
            #pragma unroll
            for (int r = 0; r < 4; ++r) {
                cst[r] = cst1[(size_t)(b0 + rg * 4 + r) * HP + col];
                xP[r] = *reinterpret_cast<const half4*>(x_p + (size_t)r * NP);
            }
            x_p += (size_t)16 * NP;
        }
        if (tid < 64) {
            int buf = tid >> 5, r2i = (tid & 31) >> 1, c8 = 112 + (tid & 1) * 8;
            *reinterpret_cast<uint4*>((buf ? hr1 : hr0) + swz(r2i, c8 * 2)) = make_uint4(0u, 0u, 0u, 0u);
        }
        if (tid >= 64 && tid < 288) {
            int i = tid - 64, row = i / 14, c8 = (i % 14) * 8;
            *reinterpret_cast<uint4*>(hr1 + swz(row, c8 * 2)) =
                *reinterpret_cast<const uint4*>(hst1 + (size_t)(b0 + row) * HP + c8);
        }
        __syncthreads();

        auto STEP1 = [&](int it, const unsigned char* rb, unsigned char* wb)
            __attribute__((always_inline)) {
            half8 af[4];
            #pragma unroll
            for (int kt = 0; kt < 4; ++kt)
                af[kt] = *reinterpret_cast<const half8*>(rb + rdo[kt]);
            f32x4 acc[4];
            #pragma unroll
            for (int g = 0; g < 4; ++g)
                #pragma unroll
                for (int r = 0; r < 4; ++r) acc[g][r] = (float)xP[r][g];
            if (it + 1 < CT) {
                #pragma unroll
                for (int r = 0; r < 4; ++r)
                    xP[r] = *reinterpret_cast<const half4*>(x_p + (size_t)r * NP);
                x_p += (size_t)16 * NP;
            }
            #pragma unroll
            for (int kt = 0; kt < 4; ++kt)
                #pragma unroll
                for (int g = 0; g < 4; ++g)
                    acc[g] = __builtin_amdgcn_mfma_f32_16x16x32_f16(af[kt], bf[g][kt], acc[g], 0, 0, 0);
            #pragma unroll
            for (int r = 0; r < 4; ++r) {
                float ig = sig2(acc[0][r]);
                float fg = sig2(acc[1][r]);
                float gg = tanh2(acc[2][r]);
                float og = sig2(acc[3][r]);
                float c = fg * cst[r] + ig * gg;
                cst[r] = c;
                float h = og * tanhc(c);
                _Float16 hf = (_Float16)h;
                *reinterpret_cast<_Float16*>(wb + wro[r]) = hf;
                *(hs_p + (size_t)r * HX) = hf;   // fire-and-forget
            }
            hs_p += (size_t)16 * HX;
        };

        for (int it = 0; it < CT; it += 2) {
            if (active) STEP1(it, hr1, hr0);
            step_barrier();
            if (active) STEP1(it + 1, hr0, hr1);
            step_barrier();
        }

        if (active) {
            #pragma unroll
            for (int r = 0; r < 4; ++r)
                cst1[(size_t)(b0 + rg * 4 + r) * HP + col] = cst[r];
        }
        if (tid < 224) {
            int row = tid / 14, c8 = (tid % 14) * 8;
            const unsigned char* sbuf = ((CT - 1) & 1) ? hr1 : hr0;
            *reinterpret_cast<uint4*>(hst1 + (size_t)(b0 + row) * HP + c8) =
                *reinterpret_cast<const uint4*>(sbuf + swz(row, c8 * 2));
        }
        return;
    }

    if (blk < 128) {
        // ================= recur layer 2 (fused gemm2), chunk k-2 =================
        if (t0r2 < 0) return;
        unsigned char* hr0 = smem;
        unsigned char* hr1 = smem + 4096;
        const int w = tid >> 6, lane = tid & 63;
        const bool active = w < 7;
        const int jb = w, l = lane & 15, rg = lane >> 4;
        const int bg = blk - 64, b0 = bg * 16;
        const int col = jb * 16 + l;

        unsigned rdo[4], wro[4];
        #pragma unroll
        for (int kt = 0; kt < 4; ++kt) rdo[kt] = swz(l, (kt * 32 + rg * 8) * 2);
        #pragma unroll
        for (int r = 0; r < 4; ++r) wro[r] = swz(rg * 4 + r, col * 2);

        half8 bi[4][4], bh[4][4];
        float b2v[4];
        float cst[4];
        half8 hP[4];
        const _Float16* hb_p = nullptr;
        float* out_p = nullptr;
        if (active) {
            #pragma unroll
            for (int g = 0; g < 4; ++g)
                #pragma unroll
                for (int kt = 0; kt < 4; ++kt) {
                    long o = (((long)(jb * 4 + g) * 4 + kt) * 64 + lane) * 8;
                    bi[g][kt] = *reinterpret_cast<const half8*>(wihf2 + o);
                    bh[g][kt] = *reinterpret_cast<const half8*>(whhf2 + o);
                }
            #pragma unroll
            for (int g = 0; g < 4; ++g) b2v[g] = bias2p[jb * 64 + g * 16 + l];
            hb_p = h1r + (size_t)bg * CT * 16 * HX + (size_t)l * HX + rg * 8;
            out_p = out + ((size_t)(b0 + rg * 4) * T_LEN + t0r2) * H + col;
            #pragma unroll
            for (int r = 0; r < 4; ++r)
                cst[r] = cst2[(size_t)(b0 + rg * 4 + r) * HP + col];
            #pragma unroll
            for (int kt = 0; kt < 4; ++kt)
                hP[kt] = *reinterpret_cast<const half8*>(hb_p + kt * 32);
        }
        if (tid < 64) {
            int buf = tid >> 5, r2i = (tid & 31) >> 1, c8 = 112 + (tid & 1) * 8;
            *reinterpret_cast<uint4*>((buf ? hr1 : hr0) + swz(r2i, c8 * 2)) = make_uint4(0u, 0u, 0u, 0u);
        }
        if (tid >= 64 && tid < 288) {
            int i = tid - 64, row = i / 14, c8 = (i % 14) * 8;
            *reinterpret_cast<uint4*>(hr1 + swz(row, c8 * 2)) =
                *reinterpret_cast<const uint4*>(hst2 + (size_t)(b0 + row) * HP + c8);
        }
        __syncthreads();

        auto STEP2 = [&](int it, const unsigned char* rb, unsigned char* wb)
            __attribute__((always_inline)) {
            half8 af2[4];
            #pragma unroll
            for (int kt = 0; kt < 4; ++kt)
                af2[kt] = *reinterpret_cast<const half8*>(rb + rdo[kt]);
            f32x4 acc[4];
            #pragma unroll
            for (int g = 0; g < 4; ++g)
                acc[g] = (f32x4){b2v[g], b2v[g], b2v[g], b2v[g]};
            // ring-independent half: h1[t] x Wih2 (registers only)
            #pragma unroll
            for (int kt = 0; kt < 4; ++kt)
                #pragma unroll
                for (int g = 0; g < 4; ++g)
                    acc[g] = __builtin_amdgcn_mfma_f32_16x16x32_f16(hP[kt], bi[g][kt], acc[g], 0, 0, 0);
            if (it + 1 < CT) {   // depth-1 prefetch of h1[t+1]
                hb_p += (size_t)16 * HX;
                #pragma unroll
                for (int kt = 0; kt < 4; ++kt)
                    hP[kt] = *reinterpret_cast<const half8*>(hb_p + kt * 32);
            }
            #pragma unroll
            for (int kt = 0; kt < 4; ++kt)
                #pragma unroll
                for (int g = 0; g < 4; ++g)
                    acc[g] = __builtin_amdgcn_mfma_f32_16x16x32_f16(af2[kt], bh[g][kt], acc[g], 0, 0, 0);
            #pragma unroll
            for (int r = 0; r < 4; ++r) {
                float ig = sig2(acc[0][r]);
                float fg = sig2(acc[1][r]);
                float gg = tanh2(acc[2][r]);
                float og = sig2(acc[3][r]);
                float c = fg * cst[r] + ig * gg;
                cst[r] = c;
                float h = og * tanhc(c);
                *reinterpret_cast<_Float16*>(wb + wro[r]) = (_Float16)h;
                if (col < H) *(out_p + (size_t)r * T_LEN * H) = h;   // fire-and-forget
            }
            out_p += H;
        };

        for (int it = 0; it < CT; it += 2) {
            if (active) STEP2(it, hr1, hr0);
            step_barrier();
            if (active) STEP2(it + 1, hr0, hr1);
            step_barrier();
        }

        if (active) {
            #pragma unroll
            for (int r = 0; r < 4; ++r)
                cst2[(size_t)(b0 + rg * 4 + r) * HP + col] = cst[r];
        }
        if (tid < 224) {
            int row = tid / 14, c8 = (tid % 14) * 8;
            const unsigned char* sbuf = ((CT - 1) & 1) ? hr1 : hr0;
            *reinterpret_cast<uint4*>(hst2 + (size_t)(b0 + row) * HP + c8) =
                *reinterpret_cast<const uint4*>(sbuf + swz(row, c8 * 2));
        }
        return;
    }

    // ================= GEMM1, chunk k: X1w[bg][tc][16][NP] = x @ Wih1'^T + bias1' =================
    if (t0g < 0) return;
    {
        unsigned char* sA = smem;
        float* sBias = reinterpret_cast<float*>(smem + 65536);
        const long row0 = (long)(blk - 128) * 256;

        {   // stage A -> f16 LDS, byte ^= (row&7)<<4
            const int r = tid >> 1, kh = (tid & 1) * 64;
            long rr = row0 + r;
            long b = rr >> LOG2CT; int tc = (int)(rr & (CT - 1));
            const float* src = x + (b * T_LEN + t0g + tc) * D_INP;
            #pragma unroll
            for (int i = 0; i < 16; ++i) {
                int k = kh + i * 4;
                float4 v = *reinterpret_cast<const float4*>(src + k);
                unsigned off = ((unsigned)r * 256u + (unsigned)k * 2u) ^ (unsigned)((r & 7) << 4);
                *reinterpret_cast<uint2*>(sA + off) = make_uint2(pack2(v.x, v.y), pack2(v.z, v.w));
            }
        }
        for (int i = tid; i < NP; i += 512) sBias[i] = bias1[i];
        __syncthreads();

        const int wv = tid >> 6, lane = tid & 63;
        const int lrow = lane & 15, lk = (lane >> 4) * 8;

        half8 aF[2][4];
        #pragma unroll
        for (int s = 0; s < 2; ++s)
            #pragma unroll
            for (int kt = 0; kt < 4; ++kt) {
                int rowL = wv * 32 + s * 16 + lrow;
                unsigned off = ((unsigned)rowL * 256u + (unsigned)(kt * 32 + lk) * 2u)
                             ^ (unsigned)((rowL & 7) << 4);
                aF[s][kt] = *reinterpret_cast<const half8*>(sA + off);
            }

        unsigned ob[2][4];
        #pragma unroll
        for (int s = 0; s < 2; ++s)
            #pragma unroll
            for (int r = 0; r < 4; ++r) {
                long rgl = row0 + wv * 32 + s * 16 + (lane >> 4) * 4 + r;
                long b = rgl >> LOG2CT; int tc = (int)(rgl & (CT - 1));
                ob[s][r] = (unsigned)((((b >> 4) * CT + tc) * 16 + (b & 15)) * NP);
            }

        for (int nt = 0; nt < NT_TILES; ++nt) {
            half8 bF[4];
            const _Float16* bp = wfrag1 + ((long)(nt * 4) * 64 + lane) * 8;
            #pragma unroll
            for (int kt = 0; kt < 4; ++kt)
                bF[kt] = *reinterpret_cast<const half8*>(bp + (long)kt * 512);

            f32x4 acc0 = {0.f, 0.f, 0.f, 0.f}, acc1 = {0.f, 0.f, 0.f, 0.f};
            #pragma unroll
            for (int kt = 0; kt < 4; ++kt) {
                acc0 = __builtin_amdgcn_mfma_f32_16x16x32_f16(aF[0][kt], bF[kt], acc0, 0, 0, 0);
                acc1 = __builtin_amdgcn_mfma_f32_16x16x32_f16(aF[1][kt], bF[kt], acc1, 0, 0, 0);
            }
            const int col = nt * 16 + lrow;                // logical: jb*64 + g*16 + l
            const int pcol = (col & ~63) | ((col & 15) << 2) | ((col >> 4) & 3); // g-fastest
            const float bv = sBias[col];
            #pragma unroll
            for (int r = 0; r < 4; ++r) {
                X1w[ob[0][r] + pcol] = (_Float16)(acc0[r] + bv);
                X1w[ob[1][r] + pcol] = (_Float16)(acc1[r] + bv);
            }
        }
    }
}

// ---------------- fp32 fallback (tiny workspace only) ----------------
__global__ __launch_bounds__(256) void lstm2_persistent(
    const float* __restrict__ x,
    const float* __restrict__ W_ih1, const float* __restrict__ W_hh1,
    const float* __restrict__ b_ih1, const float* __restrict__ b_hh1,
    const float* __restrict__ W_ih2, const float* __restrict__ W_hh2,
    const float* __restrict__ b_ih2, const float* __restrict__ b_hh2,
    float* __restrict__ out)
{
    __shared__ float s_x[4][D_INP];
    __shared__ float s_h1[4][H], s_c1[4][H], s_h2[4][H], s_c2[4][H];
    __shared__ float s_g[4][400];
    __shared__ float s_b1[400], s_b2[400];
    const int tid = threadIdx.x;
    const int row0 = blockIdx.x * 4;
    for (int i = tid; i < 400; i += 256) { s_b1[i] = b_ih1[i] + b_hh1[i]; s_b2[i] = b_ih2[i] + b_hh2[i]; }
    for (int i = tid; i < 4 * H; i += 256) { int r = i / H, jj = i % H;
        s_h1[r][jj] = 0.f; s_c1[r][jj] = 0.f; s_h2[r][jj] = 0.f; s_c2[r][jj] = 0.f; }
    __syncthreads();
    for (int t = 0; t < T_LEN; ++t) {
        for (int i = tid; i < 4 * D_INP; i += 256) { int r = i >> 7, d = i & 127;
            s_x[r][d] = x[((size_t)(row0 + r) * T_LEN + t) * D_INP + d]; }
        __syncthreads();
        for (int g = tid; g < 400; g += 256) {
            float a0, a1, a2, a3; a0 = a1 = a2 = a3 = s_b1[g];
            const float4* wi = reinterpret_cast<const float4*>(W_ih1 + (size_t)g * D_INP);
            for (int d4 = 0; d4 < D_INP / 4; ++d4) {
                float4 wv = wi[d4];
                float4 v0 = *reinterpret_cast<const float4*>(&s_x[0][d4 * 4]);
                float4 v1 = *reinterpret_cast<const float4*>(&s_x[1][d4 * 4]);
                float4 v2 = *reinterpret_cast<const float4*>(&s_x[2][d4 * 4]);
                float4 v3 = *reinterpret_cast<const float4*>(&s_x[3][d4 * 4]);
                a0 += wv.x*v0.x + wv.y*v0.y + wv.z*v0.z + wv.w*v0.w;
                a1 += wv.x*v1.x + wv.y*v1.y + wv.z*v1.z + wv.w*v1.w;
                a2 += wv.x*v2.x + wv.y*v2.y + wv.z*v2.z + wv.w*v2.w;
                a3 += wv.x*v3.x + wv.y*v3.y + wv.z*v3.z + wv.w*v3.w;
            }
            const float4* wh = reinterpret_cast<const float4*>(W_hh1 + (size_t)g * H);
            for (int k4 = 0; k4 < H / 4; ++k4) {
                float4 wv = wh[k4];
                float4 v0 = *reinterpret_cast<const float4*>(&s_h1[0][k4 * 4]);
                float4 v1 = *reinterpret_cast<const float4*>(&s_h1[1][k4 * 4]);
                float4 v2 = *reinterpret_cast<const float4*>(&s_h1[2][k4 * 4]);
                float4 v3 = *reinterpret_cast<const float4*>(&s_h1[3][k4 * 4]);
                a0 += wv.x*v0.x + wv.y*v0.y + wv.z*v0.z + wv.w*v0.w;
                a1 += wv.x*v1.x + wv.y*v1.y + wv.z*v1.z + wv.w*v1.w;
                a2 += wv.x*v2.x + wv.y*v2.y + wv.z*v2.z + wv.w*v2.w;
                a3 += wv.x*v3.x + wv.y*v3.y + wv.z*v3.z + wv.w*v3.w;
            }
            s_g[0][g] = a0; s_g[1][g] = a1; s_g[2][g] = a2; s_g[3][g] = a3;
        }
        __syncthreads();
        for (int idx = tid; idx < 4 * H; idx += 256) {
            int r = idx / H, jj = idx % H;
            float ig = fast_sigmoid(s_g[r][jj]);
            float fg = fast_sigmoid(s_g[r][H + jj]);
            float gg = fast_tanh(s_g[r][2 * H + jj]);
            float og = fast_sigmoid(s_g[r][3 * H + jj]);
            float cc = fg * s_c1[r][jj] + ig * gg;
            s_c1[r][jj] = cc; s_h1[r][jj] = og * fast_tanh(cc);
        }
        __syncthreads();
        for (int g = tid; g < 400; g += 256) {
            float a0, a1, a2, a3; a0 = a1 = a2 = a3 = s_b2[g];
            const float4* wi = reinterpret_cast<const float4*>(W_ih2 + (size_t)g * H);
            const float4* wh = reinterpret_cast<const float4*>(W_hh2 + (size_t)g * H);
            for (int k4 = 0; k4 < H / 4; ++k4) {
                float4 wv = wi[k4];
                float4 v0 = *reinterpret_cast<const float4*>(&s_h1[0][k4 * 4]);
                float4 v1 = *reinterpret_cast<const float4*>(&s_h1[1][k4 * 4]);
                float4 v2 = *reinterpret_cast<const float4*>(&s_h1[2][k4 * 4]);
                float4 v3 = *reinterpret_cast<const float4*>(&s_h1[3][k4 * 4]);
                a0 += wv.x*v0.x + wv.y*v0.y + wv.z*v0.z + wv.w*v0.w;
                a1 += wv.x*v1.x + wv.y*v1.y + wv.z*v1.z + wv.w*v1.w;
                a2 += wv.x*v2.x + wv.y*v2.y + wv.z*v2.z + wv.w*v2.w;
                a3 += wv.x*v3.x + wv.y*v3.y + wv.z*v3.z + wv.w*v3.w;
            }
            for (int k4 = 0; k4 < H / 4; ++k4) {
                float4 wv = wh[k4];
                float4 v0 = *reinterpret_cast<const float4*>(&s_h2[0][k4 * 4]);
                float4 v1 = *reinterpret_cast<const float4*>(&s_h2[1][k4 * 4]);
                float4 v2 = *reinterpret_cast<const float4*>(&s_h2[2][k4 * 4]);
                float4 v3 = *reinterpret_cast<const float4*>(&s_h2[3][k4 * 4]);
                a0 += wv.x*v0.x + wv.y*v0.y + wv.z*v0.z + wv.w*v0.w;
                a1 += wv.x*v1.x + wv.y*v1.y + wv.z*v1.z + wv.w*v1.w;
                a2 += wv.x*v2.x + wv.y*v2.y + wv.z*v2.z + wv.w*v2.w;
                a3 += wv.x*v3.x + wv.y*v3.y + wv.z*v3.z + wv.w*v3.w;
            }
            s_g[0][g] = a0; s_g[1][g] = a1; s_g[2][g] = a2; s_g[3][g] = a3;
        }
        __syncthreads();
        for (int idx = tid; idx < 4 * H; idx += 256) {
            int r = idx / H, jj = idx % H;
            float ig = fast_sigmoid(s_g[r][jj]);
            float fg = fast_sigmoid(s_g[r][H + jj]);
            float gg = fast_tanh(s_g[r][2 * H + jj]);
            float og = fast_sigmoid(s_g[r][3 * H + jj]);
            float cc = fg * s_c2[r][jj] + ig * gg;
            s_c2[r][jj] = cc;
            float hn = og * fast_tanh(cc);
            s_h2[r][jj] = hn;
            out[((size_t)(row0 + r) * T_LEN + t) * H + jj] = hn;
        }
        __syncthreads();
    }
}

// ---------------- host ----------------
template<int CT>
static void run_pipeline(const float* x, float* out,
                         _Float16* X1a, _Float16* X1b, _Float16* h1a, _Float16* h1b,
                         float* cst1, float* cst2, _Float16* hst1, _Float16* hst2,
                         const _Float16* wfrag1, const _Float16* wihf2,
                         const _Float16* whhf1, const _Float16* whhf2,
                         const float* bias1, const float* bias2,
                         hipStream_t stream)
{
    const int nCh = T_LEN / CT;
    const unsigned grid = 128u + (unsigned)((size_t)B_TOT * CT / 256);
    for (int k = 0; k <= nCh + 1; ++k) {
        int t0g  = (k < nCh) ? k * CT : -1;
        int r1on = (k >= 1 && k <= nCh) ? 1 : 0;
        int t0r2 = (k >= 2) ? (k - 2) * CT : -1;
        _Float16* X1w = (k & 1) ? X1b : X1a;
        const _Float16* X1r = (k & 1) ? X1a : X1b;          // (k-1)&1
        _Float16* h1w = (k & 1) ? h1a : h1b;                 // (k-1)&1
        const _Float16* h1r = (k & 1) ? h1b : h1a;           // (k-2)&1 = k&1
        superstep<CT><<<grid, 512, 0, stream>>>(
            x, wfrag1, bias1, X1w, X1r,
            whhf1, h1w, hst1, cst1,
            h1r, wihf2, whhf2, bias2, hst2, cst2, out,
            t0g, r1on, t0r2);
    }
}

extern "C" void kernel_launch(void* const* d_in, const int* in_sizes, int n_in,
                              void* d_out, int out_size, void* d_ws, size_t ws_size,
                              hipStream_t stream) {
    const float* x     = (const float*)d_in[0];
    const float* W_ih1 = (const float*)d_in[1];
    const float* W_hh1 = (const float*)d_in[2];
    const float* b_ih1 = (const float*)d_in[3];
    const float* b_hh1 = (const float*)d_in[4];
    const float* W_ih2 = (const float*)d_in[5];
    const float* W_hh2 = (const float*)d_in[6];
    const float* b_ih2 = (const float*)d_in[7];
    const float* b_hh2 = (const float*)d_in[8];
    float* out = (float*)d_out;

    auto need = [](int CT) -> size_t {
        return 2ull * B_TOT * CT * NP * 2         // X1 double-buffered f16
             + 2ull * B_TOT * CT * HX * 2         // h1seq double-buffered f16
             + 2ull * B_TOT * HP * 4              // c states f32
             + 2ull * B_TOT * HP * 2              // h states f16
             + 4ull * FRAG_ELEMS * 2              // weight frags f16
             + 2ull * NP * 4                      // biases
             + 256;                               // slack
    };

    int CT = 0;
    if (ws_size >= need(64)) CT = 64;
    else if (ws_size >= need(32)) CT = 32;

    if (CT == 0) {
        lstm2_persistent<<<B_TOT / 4, 256, 0, stream>>>(
            x, W_ih1, W_hh1, b_ih1, b_hh1, W_ih2, W_hh2, b_ih2, b_hh2, out);
        return;
    }

    char* p = (char*)d_ws;
    _Float16* X1a = (_Float16*)p;     p += (size_t)B_TOT * CT * NP * 2;
    _Float16* X1b = (_Float16*)p;     p += (size_t)B_TOT * CT * NP * 2;
    _Float16* h1a = (_Float16*)p;     p += (size_t)B_TOT * CT * HX * 2;
    _Float16* h1b = (_Float16*)p;     p += (size_t)B_TOT * CT * HX * 2;
    float* cst1 = (float*)p;          p += (size_t)B_TOT * HP * 4;
    float* cst2 = (float*)p;          p += (size_t)B_TOT * HP * 4;
    _Float16* hst1 = (_Float16*)p;    p += (size_t)B_TOT * HP * 2;
    _Float16* hst2 = (_Float16*)p;    p += (size_t)B_TOT * HP * 2;
    _Float16* frags = (_Float16*)p;   p += 4ull * FRAG_ELEMS * 2;
    float* biases = (float*)p;        p += 2ull * NP * 4;

    const _Float16* wfrag1 = frags;
    const _Float16* wihf2  = frags + FRAG_ELEMS;
    const _Float16* whhf1  = frags + 2ull * FRAG_ELEMS;
    const _Float16* whhf2  = frags + 3ull * FRAG_ELEMS;
    const float* bias1 = biases;
    const float* bias2 = biases + NP;

    // zero c1,c2 (f32) + h1,h2 (f16) — contiguous: 3*B*HP f32-words
    int nzero = 3 * B_TOT * HP;
    init_states<<<(nzero + 255) / 256, 256, 0, stream>>>(cst1, nzero);

    int nprep = 4 * FRAG_ELEMS + 2 * NP;
    prep_frags<<<(nprep + 255) / 256, 256, 0, stream>>>(
        W_ih1, W_ih2, W_hh1, W_hh2, b_ih1, b_hh1, b_ih2, b_hh2, frags, biases);

    if (CT == 64)
        run_pipeline<64>(x, out, X1a, X1b, h1a, h1b, cst1, cst2, hst1, hst2,
                         wfrag1, wihf2, whhf1, whhf2, bias1, bias2, stream);
    else
        run_pipeline<32>(x, out, X1a, X1b, h1a, h1b, cst1, cst2, hst1, hst2,
                         wfrag1, wihf2, whhf1, whhf2, bias1, bias2, stream);
}